// Round 2
// baseline (7907.495 us; speedup 1.0000x reference)
//
#include <hip/hip_runtime.h>
#include <math.h>

// Problem constants
#define BATCH 4
#define TSEQ  4096
#define CEMB  2048
#define NHEAD 16
#define NSEG  8
#define SEGL  512     // L: rows per (b,h,s) tile
#define DHEAD 128
#define BT    16384   // BATCH*TSEQ
#define NTILE 512     // BATCH*NHEAD*NSEG

// tile index decode: tile = ((b*16+h)*8+s)
// row l of tile -> t = h*256 + s*32 + (l>>4); col base = (l&15)*128

typedef unsigned short bf16;

__device__ __forceinline__ float elup1p(float x) {
    return x > 0.0f ? x + 1.0f : expf(x);
}
__device__ __forceinline__ float bf2f(bf16 u) {
    return __uint_as_float(((unsigned int)u) << 16);
}
__device__ __forceinline__ bf16 f2bf(float f) {
    unsigned int x = __float_as_uint(f);
    return (bf16)((x + 0x7fffu + ((x >> 16) & 1u)) >> 16);
}
__device__ __forceinline__ void ld4(const float* p, float f[4]) {
    float4 v = *(const float4*)p;
    f[0] = v.x; f[1] = v.y; f[2] = v.z; f[3] = v.w;
}
__device__ __forceinline__ void ld4(const bf16* p, float f[4]) {
    ushort4 v = *(const ushort4*)p;
    f[0] = bf2f(v.x); f[1] = bf2f(v.y); f[2] = bf2f(v.z); f[3] = bf2f(v.w);
}
__device__ __forceinline__ void st4(float* p, const float f[4]) {
    *(float4*)p = make_float4(f[0], f[1], f[2], f[3]);
}
__device__ __forceinline__ void st4(bf16* p, const float f[4]) {
    ushort4 v;
    v.x = f2bf(f[0]); v.y = f2bf(f[1]); v.z = f2bf(f[2]); v.w = f2bf(f[3]);
    *(ushort4*)p = v;
}

// ---------------------------------------------------------------------------
// GEMM: Y[M,N] = X[M,K] @ W[K,N] + bias[N], optional fused RoPE epilogue.
// 128x128 block tile, 256 threads, 8x8 micro-tile, BK=16. fp32 accumulate.
// ---------------------------------------------------------------------------
template <typename TIN, typename TOUT, bool ROPE>
__global__ __launch_bounds__(256) void gemm_kernel(
    const TIN* __restrict__ X, const float* __restrict__ W,
    const float* __restrict__ bias, TOUT* __restrict__ Y,
    int M, int N, int K) {
    __shared__ float As[16][132];
    __shared__ float Bs[16][132];
    const int tid = threadIdx.x;
    const int tx = tid & 15, ty = tid >> 4;
    const int row0 = blockIdx.y * 128;
    const int col0 = blockIdx.x * 128;
    const int ar = tid >> 2, ac = (tid & 3) << 2;   // A tile: rows ar, ar+64; cols ac..ac+3
    const int br = tid >> 5, bc = (tid & 31) << 2;  // B tile: rows br, br+8; cols bc..bc+3

    float acc[8][8];
#pragma unroll
    for (int i = 0; i < 8; ++i)
#pragma unroll
        for (int j = 0; j < 8; ++j) acc[i][j] = 0.0f;

    const TIN* Xp = X + (size_t)row0 * K;
    const float* Wp = W + col0;

    for (int k0 = 0; k0 < K; k0 += 16) {
        float a0[4], a1[4], b0[4], b1[4];
        ld4(Xp + (size_t)ar * K + (k0 + ac), a0);
        ld4(Xp + (size_t)(ar + 64) * K + (k0 + ac), a1);
        ld4(Wp + (size_t)(k0 + br) * N + bc, b0);
        ld4(Wp + (size_t)(k0 + br + 8) * N + bc, b1);
        __syncthreads();
#pragma unroll
        for (int q = 0; q < 4; ++q) {
            As[ac + q][ar] = a0[q];
            As[ac + q][ar + 64] = a1[q];
        }
        *(float4*)&Bs[br][bc] = make_float4(b0[0], b0[1], b0[2], b0[3]);
        *(float4*)&Bs[br + 8][bc] = make_float4(b1[0], b1[1], b1[2], b1[3]);
        __syncthreads();
#pragma unroll
        for (int kk = 0; kk < 16; ++kk) {
            float a[8], b[8];
            *(float4*)&a[0] = *(const float4*)&As[kk][ty * 8];
            *(float4*)&a[4] = *(const float4*)&As[kk][ty * 8 + 4];
            *(float4*)&b[0] = *(const float4*)&Bs[kk][tx * 8];
            *(float4*)&b[4] = *(const float4*)&Bs[kk][tx * 8 + 4];
#pragma unroll
            for (int i = 0; i < 8; ++i)
#pragma unroll
                for (int j = 0; j < 8; ++j) acc[i][j] += a[i] * b[j];
        }
    }

    float invf[4];
    if (ROPE) {
        const double kfreq = -0.0089944730195079925; // -ln(10000)/1024
#pragma unroll
        for (int p = 0; p < 4; ++p) {
            int j = ((col0 + tx * 8) >> 1) + p;      // pair index
            invf[p] = (float)exp((double)j * kfreq);
        }
    }

#pragma unroll
    for (int i = 0; i < 8; ++i) {
        int r = row0 + ty * 8 + i;
        int c = col0 + tx * 8;
        float ov[8];
#pragma unroll
        for (int k = 0; k < 8; ++k) ov[k] = acc[i][k] + bias[c + k];
        if (ROPE) {
            int t = r & (TSEQ - 1);
#pragma unroll
            for (int p = 0; p < 4; ++p) {
                float angf = (float)t * invf[p];     // fp32 mult mimics reference outer()
                double sd, cd;
                sincos((double)angf, &sd, &cd);
                float cs = (float)cd, sn = (float)sd;
                float a = ov[2 * p], b = ov[2 * p + 1];
                ov[2 * p] = a * cs - b * sn;
                ov[2 * p + 1] = a * sn + b * cs;
            }
        }
        st4(Y + (size_t)r * N + c, &ov[0]);
        st4(Y + (size_t)r * N + c + 4, &ov[4]);
    }
}

// ---------------------------------------------------------------------------
// Per-segment M_s[d][e] = sum_l sk[l,d]*v[l,e];  z_s[e] = sum_l sk[l,e]
// One block per (b,h,s) tile. sk = elu(k)+1. K,V are bf16.
// ---------------------------------------------------------------------------
__global__ __launch_bounds__(256) void segkv_kernel(
    const bf16* __restrict__ K, const bf16* __restrict__ V,
    float* __restrict__ Mseg, float* __restrict__ Zseg) {
    const int tile = blockIdx.x;
    const int b = tile >> 7, h = (tile >> 3) & 15, s = tile & 7;
    __shared__ float Ksh[16][132];
    __shared__ float Vsh[16][132];
    const int tid = threadIdx.x, tx = tid & 15, ty = tid >> 4;
    const int tbase = h * 256 + s * 32;
    const size_t bb = (size_t)b * TSEQ;

    float acc[8][8];
    float zacc[8];
#pragma unroll
    for (int i = 0; i < 8; ++i) {
        zacc[i] = 0.0f;
#pragma unroll
        for (int j = 0; j < 8; ++j) acc[i][j] = 0.0f;
    }

    for (int l0 = 0; l0 < SEGL; l0 += 16) {
        __syncthreads();
#pragma unroll
        for (int u = 0; u < 2; ++u) {
            int idx = tid + u * 256;          // 0..511 quad slots (16 rows x 32 quads)
            int r = idx >> 5, cb = (idx & 31) << 2;
            int l = l0 + r;
            int t = tbase + (l >> 4);
            size_t addr = (bb + t) * CEMB + (size_t)((l & 15) * 128 + cb);
            float kq[4], vq[4];
            ld4(K + addr, kq);
            ld4(V + addr, vq);
#pragma unroll
            for (int q = 0; q < 4; ++q) Ksh[r][cb + q] = elup1p(kq[q]);
            *(float4*)&Vsh[r][cb] = make_float4(vq[0], vq[1], vq[2], vq[3]);
        }
        __syncthreads();
#pragma unroll
        for (int l = 0; l < 16; ++l) {
            float a[8], bv[8];
            *(float4*)&a[0] = *(const float4*)&Ksh[l][ty * 8];
            *(float4*)&a[4] = *(const float4*)&Ksh[l][ty * 8 + 4];
            *(float4*)&bv[0] = *(const float4*)&Vsh[l][tx * 8];
            *(float4*)&bv[4] = *(const float4*)&Vsh[l][tx * 8 + 4];
#pragma unroll
            for (int i = 0; i < 8; ++i)
#pragma unroll
                for (int j = 0; j < 8; ++j) acc[i][j] += a[i] * bv[j];
            if (tx == 0) {
#pragma unroll
                for (int i = 0; i < 8; ++i) zacc[i] += a[i];
            }
        }
    }
    float* Mp = Mseg + (size_t)tile * (DHEAD * DHEAD);
#pragma unroll
    for (int i = 0; i < 8; ++i) {
        int d = ty * 8 + i;
#pragma unroll
        for (int j0 = 0; j0 < 8; j0 += 4) {
            *(float4*)&Mp[d * DHEAD + tx * 8 + j0] = make_float4(
                acc[i][j0 + 0], acc[i][j0 + 1], acc[i][j0 + 2], acc[i][j0 + 3]);
        }
    }
    if (tx == 0) {
#pragma unroll
        for (int i = 0; i < 8; ++i) Zseg[tile * DHEAD + ty * 8 + i] = zacc[i];
    }
}

// ---------------------------------------------------------------------------
// In-place exclusive prefix over segments (8) for each (b,h).
// ---------------------------------------------------------------------------
__global__ __launch_bounds__(256) void prefix_kernel(
    float* __restrict__ Mseg, float* __restrict__ Zseg) {
    const int bh = blockIdx.x;   // 0..63
    const int tid = threadIdx.x;
    for (int e = tid; e < DHEAD * DHEAD; e += 256) {
        float acc = 0.0f;
        for (int s = 0; s < NSEG; ++s) {
            size_t idx = ((size_t)(bh * NSEG + s)) * (DHEAD * DHEAD) + e;
            float tmp = Mseg[idx];
            Mseg[idx] = acc;
            acc += tmp;
        }
    }
    if (tid < DHEAD) {
        float acc = 0.0f;
        for (int s = 0; s < NSEG; ++s) {
            size_t idx = ((size_t)(bh * NSEG + s)) * DHEAD + tid;
            float tmp = Zseg[idx];
            Zseg[idx] = acc;
            acc += tmp;
        }
    }
}

// ---------------------------------------------------------------------------
// rowsum_sq[tile*512 + l] = sum_d (elu(q[l,d])+1).  Q fp32 (post-rope).
// ---------------------------------------------------------------------------
__global__ __launch_bounds__(256) void rowsum_kernel(
    const float* __restrict__ Q, float* __restrict__ Rsum) {
    const int tid = threadIdx.x;
    const int wave = tid >> 6, lane = tid & 63;
    const int rowbase = blockIdx.x * 32 + wave * 8;
#pragma unroll
    for (int rr = 0; rr < 8; ++rr) {
        int grow = rowbase + rr;             // 0 .. NTILE*SEGL-1
        int tile = grow >> 9, l = grow & 511;
        int b = tile >> 7, h = (tile >> 3) & 15, s = tile & 7;
        int t = h * 256 + s * 32 + (l >> 4);
        size_t addr = ((size_t)b * TSEQ + t) * CEMB + (size_t)((l & 15) * 128 + lane * 2);
        float2 q2 = *(const float2*)(Q + addr);
        float v = elup1p(q2.x) + elup1p(q2.y);
#pragma unroll
        for (int m = 1; m < 64; m <<= 1) v += __shfl_xor(v, m, 64);
        if (lane == 0) Rsum[grow] = v;
    }
}

// ---------------------------------------------------------------------------
// A_mem: ATT[l,e] = g * (sq @ mem)[l,e] / (rowsum_sq[l]*zvec[e] + 1e-6)
// One block = 128 rows of one tile. K dim = 128. ATT written bf16 (overwrite).
// ---------------------------------------------------------------------------
__global__ __launch_bounds__(256) void amem_kernel(
    const float* __restrict__ Q, const float* __restrict__ Mpre,
    const float* __restrict__ Zpre, const float* __restrict__ Rsum,
    const float* __restrict__ beta, bf16* __restrict__ ATT) {
    const int blk = blockIdx.x;
    const int tile = blk >> 2, chunk = blk & 3;
    const int b = tile >> 7, h = (tile >> 3) & 15, s = tile & 7;
    __shared__ float As[16][132];
    __shared__ float Bs[16][132];
    const int tid = threadIdx.x, tx = tid & 15, ty = tid >> 4;
    const int tbase = h * 256 + s * 32;
    const size_t bb = (size_t)b * TSEQ;
    const int lbase = chunk * 128;
    const float* Mp = Mpre + (size_t)tile * (DHEAD * DHEAD);
    const int ar = tid >> 2, ac = (tid & 3) << 2;
    const int br = tid >> 5, bc = (tid & 31) << 2;

    float acc[8][8];
#pragma unroll
    for (int i = 0; i < 8; ++i)
#pragma unroll
        for (int j = 0; j < 8; ++j) acc[i][j] = 0.0f;

    for (int k0 = 0; k0 < DHEAD; k0 += 16) {
        int l1 = lbase + ar;
        int t1 = tbase + (l1 >> 4);
        size_t a1 = (bb + t1) * CEMB + (size_t)((l1 & 15) * 128 + k0 + ac);
        float4 av0 = *(const float4*)(Q + a1);
        int l2 = l1 + 64;
        int t2 = tbase + (l2 >> 4);
        size_t a2 = (bb + t2) * CEMB + (size_t)((l2 & 15) * 128 + k0 + ac);
        float4 av1 = *(const float4*)(Q + a2);
        float4 b0 = *(const float4*)&Mp[(k0 + br) * DHEAD + bc];
        float4 b1 = *(const float4*)&Mp[(k0 + br + 8) * DHEAD + bc];
        __syncthreads();
        As[ac + 0][ar] = elup1p(av0.x); As[ac + 1][ar] = elup1p(av0.y);
        As[ac + 2][ar] = elup1p(av0.z); As[ac + 3][ar] = elup1p(av0.w);
        As[ac + 0][ar + 64] = elup1p(av1.x); As[ac + 1][ar + 64] = elup1p(av1.y);
        As[ac + 2][ar + 64] = elup1p(av1.z); As[ac + 3][ar + 64] = elup1p(av1.w);
        *(float4*)&Bs[br][bc] = b0;
        *(float4*)&Bs[br + 8][bc] = b1;
        __syncthreads();
#pragma unroll
        for (int kk = 0; kk < 16; ++kk) {
            float a[8], bv[8];
            *(float4*)&a[0] = *(const float4*)&As[kk][ty * 8];
            *(float4*)&a[4] = *(const float4*)&As[kk][ty * 8 + 4];
            *(float4*)&bv[0] = *(const float4*)&Bs[kk][tx * 8];
            *(float4*)&bv[4] = *(const float4*)&Bs[kk][tx * 8 + 4];
#pragma unroll
            for (int i = 0; i < 8; ++i)
#pragma unroll
                for (int j = 0; j < 8; ++j) acc[i][j] += a[i] * bv[j];
        }
    }
    const float g = 1.0f / (1.0f + expf(-beta[0]));
    const float* Zp = Zpre + (size_t)tile * DHEAD;
    float zv[8];
#pragma unroll
    for (int j = 0; j < 8; ++j) zv[j] = Zp[tx * 8 + j];
#pragma unroll
    for (int i = 0; i < 8; ++i) {
        int l = lbase + ty * 8 + i;
        float rs = Rsum[(size_t)tile * SEGL + l];
        int t = tbase + (l >> 4);
        size_t rowaddr = (bb + t) * CEMB + (size_t)((l & 15) * 128);
#pragma unroll
        for (int j0 = 0; j0 < 8; j0 += 4) {
            float o[4];
#pragma unroll
            for (int q = 0; q < 4; ++q)
                o[q] = g * acc[i][j0 + q] / (rs * zv[j0 + q] + 1e-6f);
            st4(ATT + rowaddr + tx * 8 + j0, o);
        }
    }
}

// ---------------------------------------------------------------------------
// A_dot (flash-style, no mask): ATT[l,e] += (1-g) * softmax(q k^T * scale) v.
// Block = 64 q-rows of one tile; iterate 8 chunks of 64 keys. K,V,ATT bf16.
// ---------------------------------------------------------------------------
__global__ __launch_bounds__(256) void adot_kernel(
    const float* __restrict__ Q, const bf16* __restrict__ K,
    const bf16* __restrict__ V, const float* __restrict__ beta,
    bf16* __restrict__ ATT) {
    const int blk = blockIdx.x;
    const int tile = blk >> 3, chunk = blk & 7;
    const int b = tile >> 7, h = (tile >> 3) & 15, s = tile & 7;
    __shared__ float KVs[64][132];
    __shared__ float Ps[64][68];
    const int tid = threadIdx.x, tx = tid & 15, ty = tid >> 4;
    const int tbase = h * 256 + s * 32;
    const size_t bb = (size_t)b * TSEQ;
    const int lbase = chunk * 64;
    const float scale = 0.08838834764831845f;  // 1/sqrt(128)

    size_t qrow[4];
#pragma unroll
    for (int i = 0; i < 4; ++i) {
        int l = lbase + ty * 4 + i;
        int t = tbase + (l >> 4);
        qrow[i] = (bb + t) * CEMB + (size_t)((l & 15) * 128);
    }

    float Oacc[4][8];
    float mrow[4], lrow[4];
#pragma unroll
    for (int i = 0; i < 4; ++i) {
        mrow[i] = -3.4e38f;
        lrow[i] = 0.0f;
#pragma unroll
        for (int j = 0; j < 8; ++j) Oacc[i][j] = 0.0f;
    }

    for (int kc = 0; kc < 8; ++kc) {
        __syncthreads();
        // stage K chunk (64 keys x 128 d)
#pragma unroll
        for (int u = 0; u < 8; ++u) {
            int idx = tid + u * 256;
            int r = idx >> 5, cb = (idx & 31) << 2;
            int m = kc * 64 + r;
            int t = tbase + (m >> 4);
            size_t addr = (bb + t) * CEMB + (size_t)((m & 15) * 128 + cb);
            float kq[4];
            ld4(K + addr, kq);
            *(float4*)&KVs[r][cb] = make_float4(kq[0], kq[1], kq[2], kq[3]);
        }
        __syncthreads();
        float sacc[4][4];
#pragma unroll
        for (int i = 0; i < 4; ++i)
#pragma unroll
            for (int j = 0; j < 4; ++j) sacc[i][j] = 0.0f;
#pragma unroll 4
        for (int d4 = 0; d4 < DHEAD; d4 += 4) {
            float a4[4][4], b4[4][4];
#pragma unroll
            for (int i = 0; i < 4; ++i)
                *(float4*)&a4[i][0] = *(const float4*)(Q + qrow[i] + d4);
#pragma unroll
            for (int j = 0; j < 4; ++j)
                *(float4*)&b4[j][0] = *(const float4*)&KVs[tx * 4 + j][d4];
#pragma unroll
            for (int i = 0; i < 4; ++i)
#pragma unroll
                for (int j = 0; j < 4; ++j)
                    sacc[i][j] += a4[i][0] * b4[j][0] + a4[i][1] * b4[j][1] +
                                  a4[i][2] * b4[j][2] + a4[i][3] * b4[j][3];
        }
        // online softmax update (rows are owned by a fixed 16-lane tx-group)
#pragma unroll
        for (int i = 0; i < 4; ++i) {
            float lm = -3.4e38f;
#pragma unroll
            for (int j = 0; j < 4; ++j) {
                sacc[i][j] *= scale;
                lm = fmaxf(lm, sacc[i][j]);
            }
#pragma unroll
            for (int m = 1; m < 16; m <<= 1) lm = fmaxf(lm, __shfl_xor(lm, m, 64));
            float mnew = fmaxf(mrow[i], lm);
            float alpha = expf(mrow[i] - mnew);
            float rsum = 0.0f;
#pragma unroll
            for (int j = 0; j < 4; ++j) {
                float p = expf(sacc[i][j] - mnew);
                Ps[ty * 4 + i][tx * 4 + j] = p;
                rsum += p;
            }
#pragma unroll
            for (int m = 1; m < 16; m <<= 1) rsum += __shfl_xor(rsum, m, 64);
            lrow[i] = lrow[i] * alpha + rsum;
            mrow[i] = mnew;
#pragma unroll
            for (int j = 0; j < 8; ++j) Oacc[i][j] *= alpha;
        }
        __syncthreads();
        // stage V chunk into same buffer
#pragma unroll
        for (int u = 0; u < 8; ++u) {
            int idx = tid + u * 256;
            int r = idx >> 5, cb = (idx & 31) << 2;
            int m = kc * 64 + r;
            int t = tbase + (m >> 4);
            size_t addr = (bb + t) * CEMB + (size_t)((m & 15) * 128 + cb);
            float vq[4];
            ld4(V + addr, vq);
            *(float4*)&KVs[r][cb] = make_float4(vq[0], vq[1], vq[2], vq[3]);
        }
        __syncthreads();
        // O += P @ V
#pragma unroll 4
        for (int mm = 0; mm < 64; mm += 4) {
            float p4[4][4];
#pragma unroll
            for (int i = 0; i < 4; ++i)
                *(float4*)&p4[i][0] = *(const float4*)&Ps[ty * 4 + i][mm];
#pragma unroll
            for (int q = 0; q < 4; ++q) {
                float4 v0 = *(const float4*)&KVs[mm + q][tx * 8];
                float4 v1 = *(const float4*)&KVs[mm + q][tx * 8 + 4];
#pragma unroll
                for (int i = 0; i < 4; ++i) {
                    float p = p4[i][q];
                    Oacc[i][0] += p * v0.x; Oacc[i][1] += p * v0.y;
                    Oacc[i][2] += p * v0.z; Oacc[i][3] += p * v0.w;
                    Oacc[i][4] += p * v1.x; Oacc[i][5] += p * v1.y;
                    Oacc[i][6] += p * v1.z; Oacc[i][7] += p * v1.w;
                }
            }
        }
    }
    const float g = 1.0f / (1.0f + expf(-beta[0]));
    const float omg = 1.0f - g;
#pragma unroll
    for (int i = 0; i < 4; ++i) {
        float w = omg / lrow[i];
        float x0[4], x1[4];
        ld4(ATT + qrow[i] + tx * 8, x0);
        ld4(ATT + qrow[i] + tx * 8 + 4, x1);
#pragma unroll
        for (int q = 0; q < 4; ++q) {
            x0[q] += Oacc[i][q] * w;
            x1[q] += Oacc[i][q + 4] * w;
        }
        st4(ATT + qrow[i] + tx * 8, x0);
        st4(ATT + qrow[i] + tx * 8 + 4, x1);
    }
}

// ---------------------------------------------------------------------------
extern "C" void kernel_launch(void* const* d_in, const int* in_sizes, int n_in,
                              void* d_out, int out_size, void* d_ws, size_t ws_size,
                              hipStream_t stream) {
    const float* x    = (const float*)d_in[0];
    const float* Wq   = (const float*)d_in[1];
    const float* bq   = (const float*)d_in[2];
    const float* Wk   = (const float*)d_in[3];
    const float* bk   = (const float*)d_in[4];
    const float* Wv   = (const float*)d_in[5];
    const float* bv   = (const float*)d_in[6];
    const float* Wo   = (const float*)d_in[7];
    const float* bo   = (const float*)d_in[8];
    const float* beta = (const float*)d_in[9];
    float* out = (float*)d_out;

    // Workspace layout (bytes): K bf16 64MB | V bf16 64MB | ATT bf16 64MB |
    // Mseg fp32 32MB | Zseg fp32 256KB | Rsum fp32 1MB  => ~225.3 MB total.
    char* w = (char*)d_ws;
    bf16* Kb   = (bf16*)(w);
    bf16* Vb   = (bf16*)(w + 67108864ull);
    bf16* ATTb = (bf16*)(w + 134217728ull);
    float* Mseg = (float*)(w + 201326592ull);
    float* Zseg = (float*)(w + 234881024ull);
    float* Rsum = (float*)(w + 235143168ull);
    // Q (fp32, post-rope) lives in d_out; it is dead before the final GEMM
    // overwrites d_out.
    float* Qf = out;

    dim3 gblk(CEMB / 128, BT / 128);   // (16, 128)
    gemm_kernel<float, float, true><<<gblk, 256, 0, stream>>>(x, Wq, bq, Qf, BT, CEMB, CEMB);
    gemm_kernel<float, bf16, true><<<gblk, 256, 0, stream>>>(x, Wk, bk, Kb, BT, CEMB, CEMB);
    gemm_kernel<float, bf16, false><<<gblk, 256, 0, stream>>>(x, Wv, bv, Vb, BT, CEMB, CEMB);
    segkv_kernel<<<NTILE, 256, 0, stream>>>(Kb, Vb, Mseg, Zseg);
    prefix_kernel<<<BATCH * NHEAD, 256, 0, stream>>>(Mseg, Zseg);
    rowsum_kernel<<<(NTILE * SEGL) / 32, 256, 0, stream>>>(Qf, Rsum);
    amem_kernel<<<NTILE * 4, 256, 0, stream>>>(Qf, Mseg, Zseg, Rsum, beta, ATTb);
    adot_kernel<<<NTILE * 8, 256, 0, stream>>>(Qf, Kb, Vb, beta, ATTb);
    gemm_kernel<bf16, float, false><<<gblk, 256, 0, stream>>>(ATTb, Wo, bo, out, BT, CEMB, CEMB);
}